// Round 16
// baseline (1419.316 us; speedup 1.0000x reference)
//
#include <hip/hip_runtime.h>
#include <math.h>

#define NIMG 2
#define NCAND 4630
#define MAXDET 100
#define IMG_W_F 1216.0f
#define IMG_H_F 800.0f
#define SCORE_THR 0.05f
#define NMS_THR 0.5f
#define SCALE_CLAMP_F 4.135166556742356f  // log(1000/16)

typedef __attribute__((ext_vector_type(8))) _Float16 f16x8;
typedef __attribute__((ext_vector_type(16))) float f32x16;

#define WOFF_CLS_T(i) ((unsigned)(i) * 589824u)
#define WOFF_BBX_T(i) (2359296u + (unsigned)(i) * 589824u)
#define WOFF_CLS_H 4718592u
#define WOFF_BBX_H 6488064u

#define BUF_HALFS 10944000u
#define TK_SLOT_U32 69640    // per-slot: 4096 coarse + 65536 fine + 8 sel
#define NSLOT 10

struct ConvTab {
  int cum[6];
  int H[5], W[5];
  unsigned actOff[5];
};
struct CvtTab {
  const float* f[5];
  int cumR[6];
  int H[5], W[5];
  unsigned actOff[5];
};
struct HeadTab {
  int cum[6];
  unsigned actOff[5];
  int H[5], W[5];
  long long pOffL[5];   // half-units into PH base
  long long pStride[5];
  int rOffL[5];
};
struct TKTab {
  long long pOff[NSLOT];  // half-units
  int M[NSLOT]; int kk[NSLOT]; int rBase[NSLOT]; int outBase[NSLOT];
  const float* anc[NSLOT];
};
struct PPTab {
  const float* src[10];
  unsigned dstOff[10];
  int Cout[10];
  int nCoF[10];
  int cum[11];
};
struct HaloTab {
  int cumPx[6];
  int Hp[5], Wp[5];
  unsigned actOff[5];
};

__device__ __forceinline__ unsigned short f16bits(_Float16 h) {
  union { _Float16 h; unsigned short u; } c; c.h = h; return c.u;
}
__device__ __forceinline__ float f16tof(unsigned short u) {
  union { unsigned short u; _Float16 h; } c; c.u = u; return (float)c.h;
}

// ---------------------------------------------------------------------------
// Weight prepack (all 10 convs, one dispatch)
// ---------------------------------------------------------------------------
__global__ __launch_bounds__(256)
void prepack_k(_Float16* __restrict__ dst0, PPTab tb)
{
  int t0 = blockIdx.x * 256 + threadIdx.x;
  if (t0 >= tb.cum[10]) return;
  int r = 0;
  for (int i = 1; i < 10; ++i) if (t0 >= tb.cum[i]) r = i;
  const int t = t0 - tb.cum[r];
  const float* src = tb.src[r];
  _Float16* dst = dst0 + tb.dstOff[r];
  const int Cout = tb.Cout[r], nCoF = tb.nCoF[r];

  const int l = t & 63;
  const int rest = t >> 6;
  const int coF = rest % nCoF;
  const int tc = rest / nCoF;
  const int tap = tc >> 4;
  const int cb = tc & 15;
  const int co = coF * 32 + (l & 31);
  const int ciB = cb * 16 + (l >> 5) * 8;
#pragma unroll
  for (int j = 0; j < 8; ++j) {
    float v = 0.f;
    if (co < Cout) v = src[(size_t)(co * 256 + ciB + j) * 9 + tap];
    dst[(size_t)t * 8 + j] = (_Float16)v;
  }
}

// ---------------------------------------------------------------------------
// Zero only the padding ring of the 4 act buffers.
// ---------------------------------------------------------------------------
__global__ __launch_bounds__(256)
void halo_k(_Float16* __restrict__ actBase, HaloTab tb)
{
  int t = blockIdx.x * 256 + threadIdx.x;
  if (t >= 4 * 16 * 2 * 1000) return;
  const int buf = t / 32000;
  int r = t - buf * 32000;
  const int cbimg = r / 1000;
  const int px = r - cbimg * 1000;
  const int cb = cbimg >> 1, img = cbimg & 1;
  int l = 0;
#pragma unroll
  for (int i = 1; i < 5; ++i) if (px >= tb.cumPx[i]) l = i;
  const int pxl = px - tb.cumPx[l];
  const int Hp = tb.Hp[l], Wp = tb.Wp[l];
  int hp, wp;
  if (pxl < Wp) { hp = 0; wp = pxl; }
  else if (pxl < 2 * Wp) { hp = Hp - 1; wp = pxl - Wp; }
  else { int q = pxl - 2 * Wp; hp = 1 + (q >> 1); wp = (q & 1) ? (Wp - 1) : 0; }
  const unsigned CBS = 2u * (unsigned)(Hp * Wp) * 16u;
  _Float16* a = actBase + (size_t)buf * BUF_HALFS + tb.actOff[l] +
                (unsigned)cb * CBS + ((unsigned)((img * Hp + hp) * Wp + wp)) * 16u;
  f16x8 z = {};
  *(f16x8*)(a) = z;
  *(f16x8*)(a + 8) = z;
}

// ---------------------------------------------------------------------------
// feat fp32 NCHW -> padded f16 [cb16][n][hp][wp][16ci]; all levels batched
// ---------------------------------------------------------------------------
__global__ __launch_bounds__(256)
void convert_k(_Float16* __restrict__ act, CvtTab tb)
{
  int bz = blockIdx.x;
  int l = 0;
#pragma unroll
  for (int i = 1; i < 5; ++i) if (bz >= tb.cumR[i]) l = i;
  const int h = bz - tb.cumR[l];
  const int n = blockIdx.y;
  const int H = tb.H[l], W = tb.W[l];
  const int Hp = H + 2, Wp = W + 2, HpWp = Hp * Wp;
  const unsigned CBS = 2u * (unsigned)HpWp * 16u;
  const float* x = tb.f[l];
  _Float16* a = act + tb.actOff[l];
  __shared__ float s[64][154];
  for (int c0 = 0; c0 < 256; c0 += 64) {
    for (int idx = threadIdx.x; idx < 64 * W; idx += 256) {
      int c = idx / W, w = idx - c * W;
      s[c][w] = x[((size_t)(n * 256 + c0 + c) * H + h) * W + w];
    }
    __syncthreads();
    for (int idx = threadIdx.x; idx < 4 * W; idx += 256) {
      int ch = idx / W, w = idx - ch * W;
      int cchunk = (c0 >> 4) + ch;
      unsigned base = (unsigned)cchunk * CBS +
                      ((unsigned)((n * Hp + h + 1) * Wp + (w + 1))) * 16u;
      f16x8 v0, v1;
#pragma unroll
      for (int j = 0; j < 8; ++j) {
        v0[j] = (_Float16)s[ch * 16 + j][w];
        v1[j] = (_Float16)s[ch * 16 + 8 + j][w];
      }
      *(f16x8*)(a + base) = v0;
      *(f16x8*)(a + base + 8) = v1;
    }
    __syncthreads();
  }
}

// ---------------------------------------------------------------------------
// conv inner loop (per wave): dual-cb dependency chains.
// ---------------------------------------------------------------------------
__device__ __forceinline__ void conv_core(
    const _Float16* __restrict__ in, const _Float16* __restrict__ w,
    int nCoF, int coF0, int Wp, unsigned CBS, const unsigned V0, const unsigned V1,
    unsigned lOff, f32x16& a00, f32x16& a01, f32x16& a10, f32x16& a11)
{
  const unsigned wTap = 16u * (unsigned)nCoF * 512u;
  for (int cb = 0; cb < 16; cb += 2) {
    const _Float16* aB0 = in + (unsigned)cb * CBS;
    const _Float16* aB1 = aB0 + CBS;
    const _Float16* wB0 = w + ((unsigned)cb * (unsigned)nCoF + (unsigned)coF0) * 512u;
    const _Float16* wB1 = wB0 + (unsigned)nCoF * 512u;
#pragma unroll
    for (int tap = 0; tap < 9; ++tap) {
      const unsigned to = ((unsigned)((tap / 3) * Wp + (tap % 3))) * 16u;
      const _Float16* wT0 = wB0 + (unsigned)tap * wTap;
      const _Float16* wT1 = wB1 + (unsigned)tap * wTap;
      f16x8 x0 = *(const f16x8*)(aB0 + to + V0);
      f16x8 x1 = *(const f16x8*)(aB0 + to + V1);
      f16x8 y0 = *(const f16x8*)(aB1 + to + V0);
      f16x8 y1 = *(const f16x8*)(aB1 + to + V1);
      f16x8 u0 = *(const f16x8*)(wT0 + lOff);
      f16x8 u1 = *(const f16x8*)(wT0 + 512u + lOff);
      f16x8 v0 = *(const f16x8*)(wT1 + lOff);
      f16x8 v1 = *(const f16x8*)(wT1 + 512u + lOff);
      a00 = __builtin_amdgcn_mfma_f32_32x32x16_f16(x0, u0, a00, 0, 0, 0);
      a01 = __builtin_amdgcn_mfma_f32_32x32x16_f16(x0, u1, a01, 0, 0, 0);
      a10 = __builtin_amdgcn_mfma_f32_32x32x16_f16(x1, u0, a10, 0, 0, 0);
      a11 = __builtin_amdgcn_mfma_f32_32x32x16_f16(x1, u1, a11, 0, 0, 0);
      a00 = __builtin_amdgcn_mfma_f32_32x32x16_f16(y0, v0, a00, 0, 0, 0);
      a01 = __builtin_amdgcn_mfma_f32_32x32x16_f16(y0, v1, a01, 0, 0, 0);
      a10 = __builtin_amdgcn_mfma_f32_32x32x16_f16(y1, v0, a10, 0, 0, 0);
      a11 = __builtin_amdgcn_mfma_f32_32x32x16_f16(y1, v1, a11, 0, 0, 0);
    }
  }
}

// ---------------------------------------------------------------------------
// Towers: 4-wave workgroups, 2x2 wave split (block 128m x 128co).
// ---------------------------------------------------------------------------
__global__ __launch_bounds__(256)
void tower_k(const _Float16* __restrict__ inA, const _Float16* __restrict__ inB,
             const _Float16* __restrict__ wpk,
             const float* __restrict__ biasA, const float* __restrict__ biasB,
             _Float16* __restrict__ outA, _Float16* __restrict__ outB,
             unsigned wOffA, unsigned wOffB, ConvTab tb)
{
  int bz = blockIdx.y;
  int l = 0;
#pragma unroll
  for (int i = 1; i < 5; ++i) if (bz >= tb.cum[i]) l = i;
  const int bx = bz - tb.cum[l];
  const int H = tb.H[l], W = tb.W[l];
  const int Wp = W + 2, HW = H * W, HpWp = (H + 2) * Wp;
  const unsigned CBS = 2u * (unsigned)HpWp * 16u;
  const int chain = blockIdx.x >> 1, cg2 = blockIdx.x & 1;
  const _Float16* in = (chain ? inB : inA) + tb.actOff[l];
  _Float16* out = (chain ? outB : outA) + tb.actOff[l];
  const _Float16* w = wpk + (chain ? wOffB : wOffA);
  const float* bias = chain ? biasB : biasA;
  const int Mloc = 2 * HW;

  const int wave = threadIdx.x >> 6;
  const int wr = wave & 1, wc = wave >> 1;
  const int lane = threadIdx.x & 63;
  const int lw = lane & 31;
  const int lh = lane >> 5;
  const int mBase = bx * 128 + wr * 64;
  const int coF0 = cg2 * 4 + wc * 2;
  unsigned V[2];
#pragma unroll
  for (int i = 0; i < 2; ++i) {
    int mloc = mBase + i * 32 + lw;
    if (mloc >= Mloc) mloc = Mloc - 1;
    int n = mloc / HW; int rem = mloc - n * HW;
    int h = rem / W; int ww = rem - h * W;
    V[i] = ((unsigned)(n * HpWp + h * Wp + ww)) * 16u + (unsigned)lh * 8u;
  }
  f32x16 a00 = {}, a01 = {}, a10 = {}, a11 = {};
  conv_core(in, w, 8, coF0, Wp, CBS, V[0], V[1], (unsigned)lane * 8u,
            a00, a01, a10, a11);

  const int coBase = coF0 * 32;
  const f32x16* accs[4] = {&a00, &a01, &a10, &a11};
#pragma unroll
  for (int q = 0; q < 4; ++q) {
    const f32x16& A = *accs[q];
    const int i = q >> 1, f = q & 1;
    const int co = coBase + f * 32 + lw;
    const float bv = bias[co];
#pragma unroll
    for (int r = 0; r < 16; ++r) {
      int mloc = mBase + i * 32 + ((r & 3) + 8 * (r >> 2) + 4 * lh);
      if (mloc >= Mloc) continue;
      int n = mloc / HW; int rem = mloc - n * HW;
      int h = rem / W; int ww = rem - h * W;
      unsigned addr = ((unsigned)(co >> 4)) * CBS +
                      ((unsigned)(n * HpWp + (h + 1) * Wp + (ww + 1))) * 16u +
                      (unsigned)(co & 15);
      out[addr] = (_Float16)fmaxf(A[r] + bv, 0.f);
    }
  }
}

// ---------------------------------------------------------------------------
// Heads: 2x2 wave split for cls; grid (7, m128-tiles, imgs).
// x<6: cls -> P (f16 sigmoid). x==6: bbox (wc==1 waves exit) -> R (f16).
// ---------------------------------------------------------------------------
__global__ __launch_bounds__(256)
void head_k(const _Float16* __restrict__ inC, const _Float16* __restrict__ inX,
            const _Float16* __restrict__ wpk,
            const float* __restrict__ scb, const float* __restrict__ bpb,
            _Float16* __restrict__ PH, _Float16* __restrict__ Rh, HeadTab tb)
{
  int bz = blockIdx.y;
  int li = 0;
#pragma unroll
  for (int i = 1; i < 5; ++i) if (bz >= tb.cum[i]) li = i;
  const int bx = bz - tb.cum[li];
  const int H = tb.H[li], W = tb.W[li];
  const int Wp = W + 2, HW = H * W, HpWp = (H + 2) * Wp;
  const unsigned CBS = 2u * (unsigned)HpWp * 16u;
  const int img = blockIdx.z;
  const int y = blockIdx.x;

  const int wave = threadIdx.x >> 6;
  const int wr = wave & 1, wc = wave >> 1;
  const int lane = threadIdx.x & 63;
  const int lw = lane & 31;
  const int lh = lane >> 5;

  const _Float16* in;
  const _Float16* w;
  const float* bias;
  int nCoF, coF0, Cout;
  if (y < 6) {
    in = inC + tb.actOff[li]; w = wpk + WOFF_CLS_H; bias = scb;
    nCoF = 24; coF0 = y * 4 + wc * 2; Cout = 720;
  } else {
    if (wc) return;
    in = inX + tb.actOff[li]; w = wpk + WOFF_BBX_H; bias = bpb;
    nCoF = 2; coF0 = 0; Cout = 36;
  }
  const int Mloc = HW;
  const int mBase = bx * 128 + wr * 64;
  unsigned V[2];
#pragma unroll
  for (int i = 0; i < 2; ++i) {
    int mloc = mBase + i * 32 + lw;
    if (mloc >= Mloc) mloc = Mloc - 1;
    int h = mloc / W; int ww = mloc - h * W;
    V[i] = ((unsigned)(img * HpWp + h * Wp + ww)) * 16u + (unsigned)lh * 8u;
  }
  f32x16 a00 = {}, a01 = {}, a10 = {}, a11 = {};
  conv_core(in, w, nCoF, coF0, Wp, CBS, V[0], V[1], (unsigned)lane * 8u,
            a00, a01, a10, a11);

  const long long pBase = tb.pOffL[li] + (long long)img * tb.pStride[li];
  const size_t rBase = (size_t)tb.rOffL[li] + (size_t)img * HW * 36;
  const int coBase = coF0 * 32;
  const f32x16* accs[4] = {&a00, &a01, &a10, &a11};
#pragma unroll
  for (int q = 0; q < 4; ++q) {
    const f32x16& A = *accs[q];
    const int i = q >> 1, f = q & 1;
    const int co = coBase + f * 32 + lw;
    const float bv = (co < Cout) ? bias[co] : 0.f;
#pragma unroll
    for (int r = 0; r < 16; ++r) {
      int mloc = mBase + i * 32 + ((r & 3) + 8 * (r >> 2) + 4 * lh);
      if (mloc >= Mloc) continue;
      float v = A[r] + bv;
      if (y < 6) {
        if (co < 720)
          PH[pBase + (long long)mloc * 720 + co] = (_Float16)(1.f / (1.f + expf(-v)));
      } else {
        if (co < 36) Rh[rBase + (size_t)mloc * 36 + co] = (_Float16)v;
      }
    }
  }
}

// ---------------- top-k: 2-level radix select on 16-bit f16 keys ----------------
// per-slot scratch: [coarse 4096 | fine 65536 | sel 8] u32
__global__ __launch_bounds__(256)
void hist_coarse_k(const _Float16* __restrict__ PH, unsigned* __restrict__ tkbuf, TKTab t)
{
  const int slot = blockIdx.y;
  __shared__ unsigned lh[4096];
  for (int i = threadIdx.x; i < 4096; i += 256) lh[i] = 0;
  __syncthreads();
  const _Float16* p = PH + t.pOff[slot];
  const int M = t.M[slot];
  for (int i = blockIdx.x * 256 + threadIdx.x; i < M; i += gridDim.x * 256)
    atomicAdd(&lh[f16bits(p[i]) >> 4], 1u);
  __syncthreads();
  unsigned* h = tkbuf + (size_t)slot * TK_SLOT_U32;
  for (int i = threadIdx.x; i < 4096; i += 256) {
    unsigned c = lh[i];
    if (c) atomicAdd(&h[i], c);
  }
}

__global__ __launch_bounds__(256)
void hist_fine_k(const _Float16* __restrict__ PH, unsigned* __restrict__ tkbuf, TKTab t)
{
  const int slot = blockIdx.y;
  unsigned* base = tkbuf + (size_t)slot * TK_SLOT_U32;
  const unsigned cb = base[4096 + 65536 + 0];
  const _Float16* p = PH + t.pOff[slot];
  const int M = t.M[slot];
  unsigned* h = base + 4096;
  for (int i = blockIdx.x * 256 + threadIdx.x; i < M; i += gridDim.x * 256) {
    unsigned b = f16bits(p[i]);
    if ((b >> 4) == cb) atomicAdd(&h[b], 1u);
  }
}

__global__ __launch_bounds__(1024)
void radix_scan_k(unsigned* __restrict__ tkbuf, TKTab t, int phase)
{
  const int slot = blockIdx.x;
  unsigned* base = tkbuf + (size_t)slot * TK_SLOT_U32;
  const unsigned* hb0 = base + (phase ? 4096 : 0);
  unsigned* s = base + 4096 + 65536;
  const int nbins = phase ? 65536 : 4096;
  const int k = t.kk[slot];
  const int per = nbins / 1024;
  const int tid = threadIdx.x;
  const unsigned* hb = hb0 + tid * per;
  unsigned local = 0;
  for (int i = 0; i < per; ++i) local += hb[i];
  __shared__ unsigned part[1024];
  part[tid] = local;
  __syncthreads();
  for (int d = 1; d < 1024; d <<= 1) {
    unsigned v = (tid + d < 1024) ? part[tid + d] : 0u;
    __syncthreads();
    part[tid] += v;
    __syncthreads();
  }
  unsigned above = part[tid] - local;
  unsigned kk = (phase == 0) ? (unsigned)k : ((unsigned)k - s[1]);
  if (above < kk && above + local >= kk) {
    unsigned cum = above;
    for (int i = per - 1; i >= 0; --i) {
      unsigned c = hb[i];
      if (cum + c >= kk) {
        if (phase == 0) { s[0] = (unsigned)(tid * per + i); s[1] = cum; }
        else { s[2] = (unsigned)(tid * per + i); s[4] = kk - cum; }
        break;
      }
      cum += c;
    }
  }
}

__global__ __launch_bounds__(256)
void compact_k(const _Float16* __restrict__ PH, unsigned* __restrict__ tkbuf,
               float* __restrict__ cv, unsigned* __restrict__ ci,
               unsigned* __restrict__ eq, TKTab t)
{
  const int slot = blockIdx.y;
  unsigned* s = tkbuf + (size_t)slot * TK_SLOT_U32 + 4096 + 65536;
  const unsigned thr = s[2];
  const _Float16* p = PH + t.pOff[slot];
  const int M = t.M[slot];
  float* cvn = cv + slot * 1024;
  unsigned* cin_ = ci + slot * 1024;
  unsigned* eqn = eq + (size_t)slot * 8192;
  for (int i = blockIdx.x * 256 + threadIdx.x; i < M; i += gridDim.x * 256) {
    unsigned b = f16bits(p[i]);
    if (b > thr) {
      unsigned g = atomicAdd(&s[5], 1u);
      if (g < 1024u) { cvn[g] = (float)p[i]; cin_[g] = (unsigned)i; }
    } else if (b == thr) {
      unsigned e = atomicAdd(&s[6], 1u);
      if (e < 8192u) eqn[e] = (unsigned)i;
    }
  }
}

__global__ __launch_bounds__(1024)
void finalize_k(const float* __restrict__ cv, const unsigned* __restrict__ ci,
                const unsigned* __restrict__ eq, const unsigned* __restrict__ tkbuf,
                const _Float16* __restrict__ Rh, TKTab t,
                float* __restrict__ candB, float* __restrict__ candS, float* __restrict__ candC)
{
  const int slot = blockIdx.x;
  const int tid = threadIdx.x;
  const unsigned* s = tkbuf + (size_t)slot * TK_SLOT_U32 + 4096 + 65536;
  const float* anc = t.anc[slot];
  const int k = t.kk[slot];
  __shared__ float svals[1024];
  __shared__ unsigned sidx[1024];
  __shared__ unsigned long long key[1024];
  const unsigned cntG = s[5] < 1024u ? s[5] : 1024u;
  const unsigned nEq = s[4];
  if (tid < (int)cntG) {
    svals[tid] = cv[slot * 1024 + tid];
    sidx[tid] = ci[slot * 1024 + tid];
  }
  __syncthreads();
  if (tid == 0) {
    unsigned cnt = s[6] < 8192u ? s[6] : 8192u;
    unsigned last = 0; int first = 1;
    float tv = f16tof((unsigned short)s[2]);
    for (unsigned e2 = 0; e2 < nEq && cntG + e2 < 1024u; ++e2) {
      unsigned best = 0xFFFFFFFFu;
      for (unsigned q = 0; q < cnt; ++q) {
        unsigned v = eq[(size_t)slot * 8192 + q];
        if ((first || v > last) && v < best) best = v;
      }
      svals[cntG + e2] = tv; sidx[cntG + e2] = best;
      last = best; first = 0;
    }
  }
  __syncthreads();
  const int kk = (int)cntG + (int)nEq;
  key[tid] = (tid < kk)
      ? (((unsigned long long)__float_as_uint(svals[tid]) << 32) |
         (unsigned long long)(0xFFFFFFFFu - sidx[tid]))
      : 0ULL;
  __syncthreads();
  for (int sz = 2; sz <= 1024; sz <<= 1) {
    for (int st = sz >> 1; st > 0; st >>= 1) {
      int ixj = tid ^ st;
      if (ixj > tid) {
        unsigned long long a = key[tid], b = key[ixj];
        bool up = ((tid & sz) == 0);
        if (up ? (a < b) : (a > b)) { key[tid] = b; key[ixj] = a; }
      }
      __syncthreads();
    }
  }
  if (tid < kk && tid < k) {
    unsigned long long kv = key[tid];
    float val = __uint_as_float((unsigned)(kv >> 32));
    unsigned idx = 0xFFFFFFFFu - (unsigned)(kv & 0xFFFFFFFFu);
    unsigned a = idx / 80u;
    unsigned cls = idx - a * 80u;
    const _Float16* rg = Rh + (size_t)t.rBase[slot] + (size_t)a * 4;
    float a0 = anc[(size_t)a * 4 + 0], a1 = anc[(size_t)a * 4 + 1];
    float a2 = anc[(size_t)a * 4 + 2], a3 = anc[(size_t)a * 4 + 3];
    float wa = a2 - a0, ha = a3 - a1;
    float xa = a0 + 0.5f * wa, ya = a1 + 0.5f * ha;
    float dx = (float)rg[0], dy = (float)rg[1];
    float dw = fminf((float)rg[2], SCALE_CLAMP_F), dh = fminf((float)rg[3], SCALE_CLAMP_F);
    float cx = dx * wa + xa, cy = dy * ha + ya;
    float wb = expf(dw) * wa, hb = expf(dh) * ha;
    float x0 = cx - 0.5f * wb, y0 = cy - 0.5f * hb;
    float x1 = cx + 0.5f * wb, y1 = cy + 0.5f * hb;
    x0 = fminf(fmaxf(x0, 0.f), IMG_W_F);
    y0 = fminf(fmaxf(y0, 0.f), IMG_H_F);
    x1 = fminf(fmaxf(x1, 0.f), IMG_W_F);
    y1 = fminf(fmaxf(y1, 0.f), IMG_H_F);
    int o = t.outBase[slot] + tid;
    candB[(size_t)o * 4 + 0] = x0; candB[(size_t)o * 4 + 1] = y0;
    candB[(size_t)o * 4 + 2] = x1; candB[(size_t)o * 4 + 3] = y1;
    candS[o] = (val > SCORE_THR) ? val : 0.f;
    candC[o] = (float)cls;
  }
}

// ---------------- class-aware NMS, shuffle-reduced argmax ----------------
__global__ __launch_bounds__(1024)
void nms_k(const float* __restrict__ cB, const float* __restrict__ cS,
           const float* __restrict__ cC, float* __restrict__ out)
{
  const int n = blockIdx.x;
  const int tid = threadIdx.x;
  const int wid = tid >> 6, lane = tid & 63;
  __shared__ float S[NCAND];
  __shared__ float wv_[16];
  __shared__ int wi_[16];
  __shared__ float bj[5];
  __shared__ int sjs;
  for (int i = tid; i < NCAND; i += 1024) S[i] = cS[n * NCAND + i];
  __syncthreads();
  for (int it = 0; it < MAXDET; ++it) {
    float bv = -1.f; int bix = 0;
    for (int i = tid; i < NCAND; i += 1024) {
      float v = S[i];
      if (v > bv) { bv = v; bix = i; }
    }
#pragma unroll
    for (int d = 32; d > 0; d >>= 1) {
      float v2 = __shfl_down(bv, d);
      int i2 = __shfl_down(bix, d);
      if (v2 > bv || (v2 == bv && i2 < bix)) { bv = v2; bix = i2; }
    }
    if (lane == 0) { wv_[wid] = bv; wi_[wid] = bix; }
    __syncthreads();
    if (tid < 64) {
      float v = (tid < 16) ? wv_[tid] : -2.f;
      int ix = (tid < 16) ? wi_[tid] : 0x7FFFFFFF;
#pragma unroll
      for (int d = 8; d > 0; d >>= 1) {
        float v2 = __shfl_down(v, d);
        int i2 = __shfl_down(ix, d);
        if (v2 > v || (v2 == v && i2 < ix)) { v = v2; ix = i2; }
      }
      if (tid == 0) {
        bj[4] = v; sjs = ix;
        if (v > 0.f) {
          const int j = ix;
          float b0 = cB[(size_t)(n * NCAND + j) * 4 + 0];
          float b1 = cB[(size_t)(n * NCAND + j) * 4 + 1];
          float b2 = cB[(size_t)(n * NCAND + j) * 4 + 2];
          float b3 = cB[(size_t)(n * NCAND + j) * 4 + 3];
          out[((size_t)n * MAXDET + it) * 4 + 0] = b0;
          out[((size_t)n * MAXDET + it) * 4 + 1] = b1;
          out[((size_t)n * MAXDET + it) * 4 + 2] = b2;
          out[((size_t)n * MAXDET + it) * 4 + 3] = b3;
          out[800 + n * MAXDET + it] = v;
          out[1000 + n * MAXDET + it] = cC[n * NCAND + j];
          float off = cC[n * NCAND + j] * 4096.f;
          bj[0] = b0 + off; bj[1] = b1 + off; bj[2] = b2 + off; bj[3] = b3 + off;
        }
      }
    }
    __syncthreads();
    const float mv = bj[4];
    const int j = sjs;
    if (mv <= 0.f) {
      float b0 = cB[(size_t)(n * NCAND) * 4 + 0], b1 = cB[(size_t)(n * NCAND) * 4 + 1];
      float b2 = cB[(size_t)(n * NCAND) * 4 + 2], b3 = cB[(size_t)(n * NCAND) * 4 + 3];
      float c0 = cC[n * NCAND];
      for (int t2 = it + tid; t2 < MAXDET; t2 += 1024) {
        out[((size_t)n * MAXDET + t2) * 4 + 0] = b0;
        out[((size_t)n * MAXDET + t2) * 4 + 1] = b1;
        out[((size_t)n * MAXDET + t2) * 4 + 2] = b2;
        out[((size_t)n * MAXDET + t2) * 4 + 3] = b3;
        out[800 + n * MAXDET + t2] = 0.f;
        out[1000 + n * MAXDET + t2] = c0;
      }
      return;
    }
    const float jx0 = bj[0], jy0 = bj[1], jx1 = bj[2], jy1 = bj[3];
    const float aj = (jx1 - jx0) * (jy1 - jy0);
    for (int i = tid; i < NCAND; i += 1024) {
      if (i == j) { S[i] = 0.f; continue; }
      if (S[i] == 0.f) continue;
      float off = cC[n * NCAND + i] * 4096.f;
      float x0 = cB[(size_t)(n * NCAND + i) * 4 + 0] + off;
      float y0 = cB[(size_t)(n * NCAND + i) * 4 + 1] + off;
      float x1 = cB[(size_t)(n * NCAND + i) * 4 + 2] + off;
      float y1 = cB[(size_t)(n * NCAND + i) * 4 + 3] + off;
      float lx = fmaxf(jx0, x0), ly = fmaxf(jy0, y0);
      float rx = fminf(jx1, x1), ry = fminf(jy1, y1);
      float iw = fmaxf(rx - lx, 0.f), ih = fmaxf(ry - ly, 0.f);
      float inter = iw * ih;
      float ai = (x1 - x0) * (y1 - y0);
      float iou = inter / (aj + ai - inter + 1e-9f);
      if (iou > NMS_THR) S[i] = 0.f;
    }
    __syncthreads();
  }
}

// ---------------- host ----------------
extern "C" void kernel_launch(void* const* d_in, const int* in_sizes, int n_in,
                              void* d_out, int out_size, void* d_ws, size_t ws_size,
                              hipStream_t stream)
{
  static const int LH[5] = {100, 50, 25, 13, 7};
  static const int LW[5] = {152, 76, 38, 19, 10};
  static const int LHW[5] = {15200, 3800, 950, 247, 70};
  static const int NTK[5] = {1000, 1000, 1000, 1000, 630};
  static const int OFFS[5] = {0, 1000, 2000, 3000, 4000};
  static const unsigned ACTOFF[5] = {0u, 8042496u, 10119168u, 10672128u, 10833408u};
  static const int CUMT128[6] = {0, 238, 298, 313, 317, 319};
  static const int CUMR[6] = {0, 100, 150, 175, 188, 195};
  static const int ROFF[5] = {0, 1094400, 1368000, 1436400, 1454184};
  static const int POFF14[4] = {0, 2736000, 3420000, 3597840};  // element(half) offs

  const float* feat[5]; const float* anc[5];
  for (int l = 0; l < 5; ++l) {
    feat[l] = (const float*)d_in[l];
    anc[l] = (const float*)d_in[13 + l];
  }
  const float* csw = (const float*)d_in[5];
  const float* csb = (const float*)d_in[6];
  const float* bsw = (const float*)d_in[7];
  const float* bsb = (const float*)d_in[8];
  const float* scw = (const float*)d_in[9];
  const float* scb = (const float*)d_in[10];
  const float* bpw = (const float*)d_in[11];
  const float* bpb = (const float*)d_in[12];

  float* wsF = (float*)d_ws;
  size_t o = 0;
  _Float16* actBase = (_Float16*)(wsF + o); o += (size_t)4 * BUF_HALFS / 2;
  _Float16* wpk = (_Float16*)(wsF + o); o += 3317760;
  float* P0 = wsF + o; o += 10944000;   // holds BOTH L0 images as f16
  _Float16* Rh = (_Float16*)(wsF + o); o += 729612;
  float* candB = wsF + o; o += (size_t)NIMG * NCAND * 4;
  float* candS = wsF + o; o += NIMG * NCAND;
  float* candC = wsF + o; o += NIMG * NCAND;
  float* candV = wsF + o; o += NSLOT * 1024;
  unsigned* candI = (unsigned*)(wsF + o); o += NSLOT * 1024;
  unsigned* eqI = (unsigned*)(wsF + o); o += NSLOT * 8192;
  unsigned* tkbuf = (unsigned*)(wsF + o); o += (size_t)NSLOT * TK_SLOT_U32;
  if (ws_size < o * sizeof(float)) return;  // ~142 MB required

  _Float16* X = actBase;
  _Float16* A = X + BUF_HALFS;
  _Float16* B = A + BUF_HALFS;
  _Float16* C = B + BUF_HALFS;
  _Float16* PH = actBase;  // global f16 base for P addressing (half offsets)
  float* out = (float*)d_out;

  // half-unit offsets for P regions
  const long long P0H = (long long)((_Float16*)P0 - PH);  // L0 img0; img1 at +BUF_HALFS
  const long long PXH = 0;                                 // L1-4 img0 (X L0 region)
  const long long PCH = 3LL * BUF_HALFS;                   // L1-4 img1 (C L0 region)

  // weight prepack
  {
    PPTab pp;
    static const int PPC[11] = {0, 73728, 147456, 221184, 294912, 368640,
                                442368, 516096, 589824, 811008, 829440};
    for (int i = 0; i < 11; ++i) pp.cum[i] = PPC[i];
    for (int i = 0; i < 4; ++i) {
      pp.src[i] = csw + (size_t)i * 589824; pp.dstOff[i] = WOFF_CLS_T(i);
      pp.Cout[i] = 256; pp.nCoF[i] = 8;
      pp.src[4 + i] = bsw + (size_t)i * 589824; pp.dstOff[4 + i] = WOFF_BBX_T(i);
      pp.Cout[4 + i] = 256; pp.nCoF[4 + i] = 8;
    }
    pp.src[8] = scw; pp.dstOff[8] = WOFF_CLS_H; pp.Cout[8] = 720; pp.nCoF[8] = 24;
    pp.src[9] = bpw; pp.dstOff[9] = WOFF_BBX_H; pp.Cout[9] = 36; pp.nCoF[9] = 2;
    prepack_k<<<dim3(3240), dim3(256), 0, stream>>>(wpk, pp);
  }

  // halo-ring zero
  {
    HaloTab hzt;
    static const int HCUM[6] = {0, 508, 764, 894, 962, 1000};
    for (int i = 0; i < 6; ++i) hzt.cumPx[i] = HCUM[i];
    for (int l = 0; l < 5; ++l) {
      hzt.Hp[l] = LH[l] + 2; hzt.Wp[l] = LW[l] + 2; hzt.actOff[l] = ACTOFF[l];
    }
    halo_k<<<dim3((128000 + 255) / 256), dim3(256), 0, stream>>>(X, hzt);
  }

  ConvTab ct;
  CvtTab vt;
  for (int l = 0; l < 5; ++l) {
    ct.H[l] = LH[l]; ct.W[l] = LW[l]; ct.actOff[l] = ACTOFF[l];
    vt.f[l] = feat[l]; vt.H[l] = LH[l]; vt.W[l] = LW[l]; vt.actOff[l] = ACTOFF[l];
  }
  for (int i = 0; i < 6; ++i) { ct.cum[i] = CUMT128[i]; vt.cumR[i] = CUMR[i]; }

  convert_k<<<dim3(195, NIMG), dim3(256), 0, stream>>>(X, vt);

  // towers
  tower_k<<<dim3(4, 319), dim3(256), 0, stream>>>(X, X, wpk, csb + 0, bsb + 0, A, B,
      WOFF_CLS_T(0), WOFF_BBX_T(0), ct);
  tower_k<<<dim3(4, 319), dim3(256), 0, stream>>>(A, B, wpk, csb + 256, bsb + 256, C, X,
      WOFF_CLS_T(1), WOFF_BBX_T(1), ct);
  tower_k<<<dim3(4, 319), dim3(256), 0, stream>>>(C, X, wpk, csb + 512, bsb + 512, A, B,
      WOFF_CLS_T(2), WOFF_BBX_T(2), ct);
  tower_k<<<dim3(4, 319), dim3(256), 0, stream>>>(A, B, wpk, csb + 768, bsb + 768, C, X,
      WOFF_CLS_T(3), WOFF_BBX_T(3), ct);
  // cls acts in C, bbox acts in X

  // ---- heads (2 dispatches) ----
  {
    HeadTab ht = {};
    ht.cum[0] = 0; ht.cum[1] = 119;
    for (int i = 2; i < 6; ++i) ht.cum[i] = 0x7FFFFFFF;
    ht.actOff[0] = ACTOFF[0]; ht.H[0] = LH[0]; ht.W[0] = LW[0];
    ht.pOffL[0] = P0H; ht.pStride[0] = (long long)BUF_HALFS;
    ht.rOffL[0] = ROFF[0];
    head_k<<<dim3(7, 119, 2), dim3(256), 0, stream>>>(C, X, wpk, scb, bpb, PH, Rh, ht);
  }
  {
    HeadTab ht = {};
    static const int CUMH14[6] = {0, 30, 38, 40, 41, 0x7FFFFFFF};
    for (int i = 0; i < 6; ++i) ht.cum[i] = CUMH14[i];
    for (int i = 0; i < 4; ++i) {
      int l = i + 1;
      ht.actOff[i] = ACTOFF[l]; ht.H[i] = LH[l]; ht.W[i] = LW[l];
      ht.pOffL[i] = PXH + POFF14[i];
      ht.pStride[i] = PCH - PXH;
      ht.rOffL[i] = ROFF[l];
    }
    head_k<<<dim3(7, 41, 2), dim3(256), 0, stream>>>(C, X, wpk, scb, bpb, PH, Rh, ht);
  }

  // ---- single 10-slot top-k batch (f16 keys) ----
  {
    TKTab tk = {};
    tk.pOff[0] = P0H; tk.pOff[1] = P0H + (long long)BUF_HALFS;
    for (int img = 0; img < 2; ++img) {
      tk.M[img] = LHW[0] * 720; tk.kk[img] = NTK[0];
      tk.rBase[img] = ROFF[0] + img * LHW[0] * 36;
      tk.outBase[img] = img * NCAND + OFFS[0];
      tk.anc[img] = anc[0];
    }
    for (int s = 2; s < 10; ++s) {
      int i = s - 2;
      int l = (i & 3) + 1, img = i >> 2;
      tk.pOff[s] = (img ? PCH : PXH) + POFF14[l - 1];
      tk.M[s] = LHW[l] * 720;
      tk.kk[s] = NTK[l];
      tk.rBase[s] = ROFF[l] + img * LHW[l] * 36;
      tk.outBase[s] = img * NCAND + OFFS[l];
      tk.anc[s] = anc[l];
    }
    hipMemsetAsync(tkbuf, 0, (size_t)NSLOT * TK_SLOT_U32 * 4, stream);
    hist_coarse_k<<<dim3(256, NSLOT), dim3(256), 0, stream>>>(PH, tkbuf, tk);
    radix_scan_k<<<dim3(NSLOT), dim3(1024), 0, stream>>>(tkbuf, tk, 0);
    hist_fine_k<<<dim3(256, NSLOT), dim3(256), 0, stream>>>(PH, tkbuf, tk);
    radix_scan_k<<<dim3(NSLOT), dim3(1024), 0, stream>>>(tkbuf, tk, 1);
    compact_k<<<dim3(256, NSLOT), dim3(256), 0, stream>>>(PH, tkbuf, candV, candI, eqI, tk);
    finalize_k<<<dim3(NSLOT), dim3(1024), 0, stream>>>(candV, candI, eqI, tkbuf, Rh, tk,
                                                       candB, candS, candC);
  }
  nms_k<<<dim3(NIMG), dim3(1024), 0, stream>>>(candB, candS, candC, out);
}

// Round 17
// 1331.489 us; speedup vs baseline: 1.0660x; 1.0660x over previous
//
#include <hip/hip_runtime.h>
#include <math.h>

#define NIMG 2
#define NCAND 4630
#define MAXDET 100
#define IMG_W_F 1216.0f
#define IMG_H_F 800.0f
#define SCORE_THR 0.05f
#define NMS_THR 0.5f
#define SCALE_CLAMP_F 4.135166556742356f  // log(1000/16)

typedef __attribute__((ext_vector_type(8))) _Float16 f16x8;
typedef __attribute__((ext_vector_type(16))) float f32x16;

#define WOFF_CLS_T(i) ((unsigned)(i) * 589824u)
#define WOFF_BBX_T(i) (2359296u + (unsigned)(i) * 589824u)
#define WOFF_CLS_H 4718592u
#define WOFF_BBX_H 6488064u

#define BUF_HALFS 10944000u   // per act buffer; A+B region == one L0 P (f32)
#define TK_SLOT_U32 139272    // per-slot scratch: 8192 histC + 131072 histF + 8 sel
#define NSLOT 10

struct ConvTab {
  int cum[6];
  int H[5], W[5];
  unsigned actOff[5];
};
struct CvtTab {
  const float* f[5];
  int cumR[6];
  int H[5], W[5];
  unsigned actOff[5];
};
struct HeadTab {
  int cum[6];
  unsigned actOff[5];
  int H[5], W[5];
  int pOffL[5];
  int pStride[5];
  int rOffL[5];
};
struct TKTab {
  int pOff[NSLOT]; int M[NSLOT]; int kk[NSLOT]; int rBase[NSLOT]; int outBase[NSLOT];
  const float* anc[NSLOT];
};
struct PPTab {
  const float* src[10];
  unsigned dstOff[10];
  int Cout[10];
  int nCoF[10];
  int cum[11];
};
struct HaloTab {
  int cumPx[6];        // ring-pixel cumsum per level {0,508,764,894,962,1000}
  int Hp[5], Wp[5];
  unsigned actOff[5];
};

// ---------------------------------------------------------------------------
// Weight prepack (all 10 convs, one dispatch)
// ---------------------------------------------------------------------------
__global__ __launch_bounds__(256)
void prepack_k(_Float16* __restrict__ dst0, PPTab tb)
{
  int t0 = blockIdx.x * 256 + threadIdx.x;
  if (t0 >= tb.cum[10]) return;
  int r = 0;
  for (int i = 1; i < 10; ++i) if (t0 >= tb.cum[i]) r = i;
  const int t = t0 - tb.cum[r];
  const float* src = tb.src[r];
  _Float16* dst = dst0 + tb.dstOff[r];
  const int Cout = tb.Cout[r], nCoF = tb.nCoF[r];

  const int l = t & 63;
  const int rest = t >> 6;
  const int coF = rest % nCoF;
  const int tc = rest / nCoF;
  const int tap = tc >> 4;
  const int cb = tc & 15;
  const int co = coF * 32 + (l & 31);
  const int ciB = cb * 16 + (l >> 5) * 8;
#pragma unroll
  for (int j = 0; j < 8; ++j) {
    float v = 0.f;
    if (co < Cout) v = src[(size_t)(co * 256 + ciB + j) * 9 + tap];
    dst[(size_t)t * 8 + j] = (_Float16)v;
  }
}

// ---------------------------------------------------------------------------
// Zero only the padding ring of the 4 act buffers.
// ---------------------------------------------------------------------------
__global__ __launch_bounds__(256)
void halo_k(_Float16* __restrict__ actBase, HaloTab tb)
{
  int t = blockIdx.x * 256 + threadIdx.x;
  if (t >= 4 * 16 * 2 * 1000) return;
  const int buf = t / 32000;
  int r = t - buf * 32000;
  const int cbimg = r / 1000;
  const int px = r - cbimg * 1000;
  const int cb = cbimg >> 1, img = cbimg & 1;
  int l = 0;
#pragma unroll
  for (int i = 1; i < 5; ++i) if (px >= tb.cumPx[i]) l = i;
  const int pxl = px - tb.cumPx[l];
  const int Hp = tb.Hp[l], Wp = tb.Wp[l];
  int hp, wp;
  if (pxl < Wp) { hp = 0; wp = pxl; }
  else if (pxl < 2 * Wp) { hp = Hp - 1; wp = pxl - Wp; }
  else { int q = pxl - 2 * Wp; hp = 1 + (q >> 1); wp = (q & 1) ? (Wp - 1) : 0; }
  const unsigned CBS = 2u * (unsigned)(Hp * Wp) * 16u;
  _Float16* a = actBase + (size_t)buf * BUF_HALFS + tb.actOff[l] +
                (unsigned)cb * CBS + ((unsigned)((img * Hp + hp) * Wp + wp)) * 16u;
  f16x8 z = {};
  *(f16x8*)(a) = z;
  *(f16x8*)(a + 8) = z;
}

// ---------------------------------------------------------------------------
// feat fp32 NCHW -> padded f16 [cb16][n][hp][wp][16ci]; all levels batched
// ---------------------------------------------------------------------------
__global__ __launch_bounds__(256)
void convert_k(_Float16* __restrict__ act, CvtTab tb)
{
  int bz = blockIdx.x;
  int l = 0;
#pragma unroll
  for (int i = 1; i < 5; ++i) if (bz >= tb.cumR[i]) l = i;
  const int h = bz - tb.cumR[l];
  const int n = blockIdx.y;
  const int H = tb.H[l], W = tb.W[l];
  const int Hp = H + 2, Wp = W + 2, HpWp = Hp * Wp;
  const unsigned CBS = 2u * (unsigned)HpWp * 16u;
  const float* x = tb.f[l];
  _Float16* a = act + tb.actOff[l];
  __shared__ float s[64][154];
  for (int c0 = 0; c0 < 256; c0 += 64) {
    for (int idx = threadIdx.x; idx < 64 * W; idx += 256) {
      int c = idx / W, w = idx - c * W;
      s[c][w] = x[((size_t)(n * 256 + c0 + c) * H + h) * W + w];
    }
    __syncthreads();
    for (int idx = threadIdx.x; idx < 4 * W; idx += 256) {
      int ch = idx / W, w = idx - ch * W;
      int cchunk = (c0 >> 4) + ch;
      unsigned base = (unsigned)cchunk * CBS +
                      ((unsigned)((n * Hp + h + 1) * Wp + (w + 1))) * 16u;
      f16x8 v0, v1;
#pragma unroll
      for (int j = 0; j < 8; ++j) {
        v0[j] = (_Float16)s[ch * 16 + j][w];
        v1[j] = (_Float16)s[ch * 16 + 8 + j][w];
      }
      *(f16x8*)(a + base) = v0;
      *(f16x8*)(a + base + 8) = v1;
    }
    __syncthreads();
  }
}

// ---------------------------------------------------------------------------
// conv inner loop (per wave): dual-cb dependency chains (proven R10 shape).
// ---------------------------------------------------------------------------
__device__ __forceinline__ void conv_core(
    const _Float16* __restrict__ in, const _Float16* __restrict__ w,
    int nCoF, int coF0, int Wp, unsigned CBS, const unsigned V0, const unsigned V1,
    unsigned lOff, f32x16& a00, f32x16& a01, f32x16& a10, f32x16& a11)
{
  const unsigned wTap = 16u * (unsigned)nCoF * 512u;
  for (int cb = 0; cb < 16; cb += 2) {
    const _Float16* aB0 = in + (unsigned)cb * CBS;
    const _Float16* aB1 = aB0 + CBS;
    const _Float16* wB0 = w + ((unsigned)cb * (unsigned)nCoF + (unsigned)coF0) * 512u;
    const _Float16* wB1 = wB0 + (unsigned)nCoF * 512u;
#pragma unroll
    for (int tap = 0; tap < 9; ++tap) {
      const unsigned to = ((unsigned)((tap / 3) * Wp + (tap % 3))) * 16u;
      const _Float16* wT0 = wB0 + (unsigned)tap * wTap;
      const _Float16* wT1 = wB1 + (unsigned)tap * wTap;
      f16x8 x0 = *(const f16x8*)(aB0 + to + V0);
      f16x8 x1 = *(const f16x8*)(aB0 + to + V1);
      f16x8 y0 = *(const f16x8*)(aB1 + to + V0);
      f16x8 y1 = *(const f16x8*)(aB1 + to + V1);
      f16x8 u0 = *(const f16x8*)(wT0 + lOff);
      f16x8 u1 = *(const f16x8*)(wT0 + 512u + lOff);
      f16x8 v0 = *(const f16x8*)(wT1 + lOff);
      f16x8 v1 = *(const f16x8*)(wT1 + 512u + lOff);
      a00 = __builtin_amdgcn_mfma_f32_32x32x16_f16(x0, u0, a00, 0, 0, 0);
      a01 = __builtin_amdgcn_mfma_f32_32x32x16_f16(x0, u1, a01, 0, 0, 0);
      a10 = __builtin_amdgcn_mfma_f32_32x32x16_f16(x1, u0, a10, 0, 0, 0);
      a11 = __builtin_amdgcn_mfma_f32_32x32x16_f16(x1, u1, a11, 0, 0, 0);
      a00 = __builtin_amdgcn_mfma_f32_32x32x16_f16(y0, v0, a00, 0, 0, 0);
      a01 = __builtin_amdgcn_mfma_f32_32x32x16_f16(y0, v1, a01, 0, 0, 0);
      a10 = __builtin_amdgcn_mfma_f32_32x32x16_f16(y1, v0, a10, 0, 0, 0);
      a11 = __builtin_amdgcn_mfma_f32_32x32x16_f16(y1, v1, a11, 0, 0, 0);
    }
  }
}

// ---------------------------------------------------------------------------
// Towers: 4-wave workgroups, 2x2 wave split: block = 128m x 128co,
// wave = 64m x 64co (wr=wave&1 m-half, wc=wave>>1 co-half).
// grid: (4, m-tiles(128) cum[5]); x = chain*2 + cg2 fastest.
// ---------------------------------------------------------------------------
__global__ __launch_bounds__(256)
void tower_k(const _Float16* __restrict__ inA, const _Float16* __restrict__ inB,
             const _Float16* __restrict__ wpk,
             const float* __restrict__ biasA, const float* __restrict__ biasB,
             _Float16* __restrict__ outA, _Float16* __restrict__ outB,
             unsigned wOffA, unsigned wOffB, ConvTab tb)
{
  int bz = blockIdx.y;
  int l = 0;
#pragma unroll
  for (int i = 1; i < 5; ++i) if (bz >= tb.cum[i]) l = i;
  const int bx = bz - tb.cum[l];
  const int H = tb.H[l], W = tb.W[l];
  const int Wp = W + 2, HW = H * W, HpWp = (H + 2) * Wp;
  const unsigned CBS = 2u * (unsigned)HpWp * 16u;
  const int chain = blockIdx.x >> 1, cg2 = blockIdx.x & 1;
  const _Float16* in = (chain ? inB : inA) + tb.actOff[l];
  _Float16* out = (chain ? outB : outA) + tb.actOff[l];
  const _Float16* w = wpk + (chain ? wOffB : wOffA);
  const float* bias = chain ? biasB : biasA;
  const int Mloc = 2 * HW;

  const int wave = threadIdx.x >> 6;
  const int wr = wave & 1, wc = wave >> 1;
  const int lane = threadIdx.x & 63;
  const int lw = lane & 31;
  const int lh = lane >> 5;
  const int mBase = bx * 128 + wr * 64;
  const int coF0 = cg2 * 4 + wc * 2;
  unsigned V[2];
#pragma unroll
  for (int i = 0; i < 2; ++i) {
    int mloc = mBase + i * 32 + lw;
    if (mloc >= Mloc) mloc = Mloc - 1;
    int n = mloc / HW; int rem = mloc - n * HW;
    int h = rem / W; int ww = rem - h * W;
    V[i] = ((unsigned)(n * HpWp + h * Wp + ww)) * 16u + (unsigned)lh * 8u;
  }
  f32x16 a00 = {}, a01 = {}, a10 = {}, a11 = {};
  conv_core(in, w, 8, coF0, Wp, CBS, V[0], V[1], (unsigned)lane * 8u,
            a00, a01, a10, a11);

  const int coBase = coF0 * 32;
  const f32x16* accs[4] = {&a00, &a01, &a10, &a11};
#pragma unroll
  for (int q = 0; q < 4; ++q) {
    const f32x16& A = *accs[q];
    const int i = q >> 1, f = q & 1;
    const int co = coBase + f * 32 + lw;
    const float bv = bias[co];
#pragma unroll
    for (int r = 0; r < 16; ++r) {
      int mloc = mBase + i * 32 + ((r & 3) + 8 * (r >> 2) + 4 * lh);
      if (mloc >= Mloc) continue;
      int n = mloc / HW; int rem = mloc - n * HW;
      int h = rem / W; int ww = rem - h * W;
      unsigned addr = ((unsigned)(co >> 4)) * CBS +
                      ((unsigned)(n * HpWp + (h + 1) * Wp + (ww + 1))) * 16u +
                      (unsigned)(co & 15);
      out[addr] = (_Float16)fmaxf(A[r] + bv, 0.f);
    }
  }
}

// ---------------------------------------------------------------------------
// Heads: 4-wave workgroups; grid (13, m4-tiles, imgs); x fastest.
// x<12: cls->P(sigmoid); x==12: bbox->R(f16)
// pBase = pOffL + z*pStride (signed 64-bit arithmetic)
// ---------------------------------------------------------------------------
__global__ __launch_bounds__(256)
void head_k(const _Float16* __restrict__ inC, const _Float16* __restrict__ inX,
            const _Float16* __restrict__ wpk,
            const float* __restrict__ scb, const float* __restrict__ bpb,
            float* __restrict__ P, _Float16* __restrict__ Rh, HeadTab tb)
{
  int bz = blockIdx.y;
  int li = 0;
#pragma unroll
  for (int i = 1; i < 5; ++i) if (bz >= tb.cum[i]) li = i;
  const int bx = bz - tb.cum[li];
  const int H = tb.H[li], W = tb.W[li];
  const int Wp = W + 2, HW = H * W, HpWp = (H + 2) * Wp;
  const unsigned CBS = 2u * (unsigned)HpWp * 16u;
  const int img = blockIdx.z;
  const int y = blockIdx.x;

  const _Float16* in;
  const _Float16* w;
  const float* bias;
  int nCoF, coF0, coBase, Cout;
  if (y < 12) {
    in = inC + tb.actOff[li]; w = wpk + WOFF_CLS_H; bias = scb;
    nCoF = 24; coF0 = y * 2; coBase = y * 64; Cout = 720;
  } else {
    in = inX + tb.actOff[li]; w = wpk + WOFF_BBX_H; bias = bpb;
    nCoF = 2; coF0 = 0; coBase = 0; Cout = 36;
  }
  const int Mloc = HW;
  const int wave = threadIdx.x >> 6;
  const int lane = threadIdx.x & 63;
  const int lw = lane & 31;
  const int lh = lane >> 5;
  const int mBase = bx * 256 + wave * 64;
  unsigned V[2];
#pragma unroll
  for (int i = 0; i < 2; ++i) {
    int mloc = mBase + i * 32 + lw;
    if (mloc >= Mloc) mloc = Mloc - 1;
    int h = mloc / W; int ww = mloc - h * W;
    V[i] = ((unsigned)(img * HpWp + h * Wp + ww)) * 16u + (unsigned)lh * 8u;
  }
  f32x16 a00 = {}, a01 = {}, a10 = {}, a11 = {};
  conv_core(in, w, nCoF, coF0, Wp, CBS, V[0], V[1], (unsigned)lane * 8u,
            a00, a01, a10, a11);

  const long long pBase = (long long)tb.pOffL[li] +
                          (long long)img * (long long)tb.pStride[li];
  const size_t rBase = (size_t)tb.rOffL[li] + (size_t)img * HW * 36;
  const f32x16* accs[4] = {&a00, &a01, &a10, &a11};
#pragma unroll
  for (int q = 0; q < 4; ++q) {
    const f32x16& A = *accs[q];
    const int i = q >> 1, f = q & 1;
    const int co = coBase + f * 32 + lw;
    const float bv = (co < Cout) ? bias[co] : 0.f;
#pragma unroll
    for (int r = 0; r < 16; ++r) {
      int mloc = mBase + i * 32 + ((r & 3) + 8 * (r >> 2) + 4 * lh);
      if (mloc >= Mloc) continue;
      float v = A[r] + bv;
      if (y < 12) {
        if (co < 720) P[pBase + (long long)mloc * 720 + co] = 1.f / (1.f + expf(-v));
      } else {
        if (co < 36) Rh[rBase + (size_t)mloc * 36 + co] = (_Float16)v;
      }
    }
  }
}

// ---------------- top-k: 2-level radix select, slot-batched ----------------
__global__ __launch_bounds__(256)
void hist_coarse_k(const float* __restrict__ wsF, unsigned* __restrict__ tkbuf, TKTab t)
{
  const int slot = blockIdx.y;
  __shared__ unsigned lh[8192];
  for (int i = threadIdx.x; i < 8192; i += 256) lh[i] = 0;
  __syncthreads();
  const float* p = wsF + t.pOff[slot];
  const int M = t.M[slot];
  for (int i = blockIdx.x * 256 + threadIdx.x; i < M; i += gridDim.x * 256)
    atomicAdd(&lh[(__float_as_uint(p[i]) >> 17) & 8191u], 1u);
  __syncthreads();
  unsigned* h = tkbuf + (size_t)slot * TK_SLOT_U32;
  for (int i = threadIdx.x; i < 8192; i += 256) {
    unsigned c = lh[i];
    if (c) atomicAdd(&h[i], c);
  }
}

__global__ __launch_bounds__(256)
void hist_fine_k(const float* __restrict__ wsF, unsigned* __restrict__ tkbuf, TKTab t)
{
  const int slot = blockIdx.y;
  unsigned* base = tkbuf + (size_t)slot * TK_SLOT_U32;
  const unsigned cb = base[8192 + 131072 + 0];
  const float* p = wsF + t.pOff[slot];
  const int M = t.M[slot];
  unsigned* h = base + 8192;
  for (int i = blockIdx.x * 256 + threadIdx.x; i < M; i += gridDim.x * 256) {
    unsigned b = __float_as_uint(p[i]);
    if ((b >> 17) == cb) atomicAdd(&h[b & 0x1FFFFu], 1u);
  }
}

__global__ __launch_bounds__(1024)
void radix_scan_k(unsigned* __restrict__ tkbuf, TKTab t, int phase)
{
  const int slot = blockIdx.x;
  unsigned* base = tkbuf + (size_t)slot * TK_SLOT_U32;
  const unsigned* hb0 = base + (phase ? 8192 : 0);
  unsigned* s = base + 8192 + 131072;
  const int nbins = phase ? 131072 : 8192;
  const int k = t.kk[slot];
  const int per = nbins / 1024;
  const int tid = threadIdx.x;
  const unsigned* hb = hb0 + tid * per;
  unsigned local = 0;
  for (int i = 0; i < per; ++i) local += hb[i];
  __shared__ unsigned part[1024];
  part[tid] = local;
  __syncthreads();
  for (int d = 1; d < 1024; d <<= 1) {
    unsigned v = (tid + d < 1024) ? part[tid + d] : 0u;
    __syncthreads();
    part[tid] += v;
    __syncthreads();
  }
  unsigned above = part[tid] - local;
  unsigned kk = (phase == 0) ? (unsigned)k : ((unsigned)k - s[1]);
  if (above < kk && above + local >= kk) {
    unsigned cum = above;
    for (int i = per - 1; i >= 0; --i) {
      unsigned c = hb[i];
      if (cum + c >= kk) {
        if (phase == 0) { s[0] = (unsigned)(tid * per + i); s[1] = cum; }
        else { s[2] = (s[0] << 17) | (unsigned)(tid * per + i); s[4] = kk - cum; }
        break;
      }
      cum += c;
    }
  }
}

__global__ __launch_bounds__(256)
void compact_k(const float* __restrict__ wsF, unsigned* __restrict__ tkbuf,
               float* __restrict__ cv, unsigned* __restrict__ ci,
               unsigned* __restrict__ eq, TKTab t)
{
  const int slot = blockIdx.y;
  unsigned* s = tkbuf + (size_t)slot * TK_SLOT_U32 + 8192 + 131072;
  const unsigned thr = s[2];
  const float* p = wsF + t.pOff[slot];
  const int M = t.M[slot];
  float* cvn = cv + slot * 1024;
  unsigned* cin_ = ci + slot * 1024;
  unsigned* eqn = eq + (size_t)slot * 8192;
  for (int i = blockIdx.x * 256 + threadIdx.x; i < M; i += gridDim.x * 256) {
    unsigned b = __float_as_uint(p[i]);
    if (b > thr) {
      unsigned g = atomicAdd(&s[5], 1u);
      if (g < 1024u) { cvn[g] = p[i]; cin_[g] = (unsigned)i; }
    } else if (b == thr) {
      unsigned e = atomicAdd(&s[6], 1u);
      if (e < 8192u) eqn[e] = (unsigned)i;
    }
  }
}

__global__ __launch_bounds__(1024)
void finalize_k(const float* __restrict__ cv, const unsigned* __restrict__ ci,
                const unsigned* __restrict__ eq, const unsigned* __restrict__ tkbuf,
                const _Float16* __restrict__ Rh, TKTab t,
                float* __restrict__ candB, float* __restrict__ candS, float* __restrict__ candC)
{
  const int slot = blockIdx.x;
  const int tid = threadIdx.x;
  const unsigned* s = tkbuf + (size_t)slot * TK_SLOT_U32 + 8192 + 131072;
  const float* anc = t.anc[slot];
  const int k = t.kk[slot];
  __shared__ float svals[1024];
  __shared__ unsigned sidx[1024];
  __shared__ unsigned long long key[1024];
  const unsigned cntG = s[5] < 1024u ? s[5] : 1024u;
  const unsigned nEq = s[4];
  if (tid < (int)cntG) {
    svals[tid] = cv[slot * 1024 + tid];
    sidx[tid] = ci[slot * 1024 + tid];
  }
  __syncthreads();
  if (tid == 0) {
    unsigned cnt = s[6] < 8192u ? s[6] : 8192u;
    unsigned last = 0; int first = 1;
    float tv = __uint_as_float(s[2]);
    for (unsigned e2 = 0; e2 < nEq && cntG + e2 < 1024u; ++e2) {
      unsigned best = 0xFFFFFFFFu;
      for (unsigned q = 0; q < cnt; ++q) {
        unsigned v = eq[(size_t)slot * 8192 + q];
        if ((first || v > last) && v < best) best = v;
      }
      svals[cntG + e2] = tv; sidx[cntG + e2] = best;
      last = best; first = 0;
    }
  }
  __syncthreads();
  const int kk = (int)cntG + (int)nEq;
  key[tid] = (tid < kk)
      ? (((unsigned long long)__float_as_uint(svals[tid]) << 32) |
         (unsigned long long)(0xFFFFFFFFu - sidx[tid]))
      : 0ULL;
  __syncthreads();
  for (int sz = 2; sz <= 1024; sz <<= 1) {
    for (int st = sz >> 1; st > 0; st >>= 1) {
      int ixj = tid ^ st;
      if (ixj > tid) {
        unsigned long long a = key[tid], b = key[ixj];
        bool up = ((tid & sz) == 0);
        if (up ? (a < b) : (a > b)) { key[tid] = b; key[ixj] = a; }
      }
      __syncthreads();
    }
  }
  if (tid < kk && tid < k) {
    unsigned long long kv = key[tid];
    float val = __uint_as_float((unsigned)(kv >> 32));
    unsigned idx = 0xFFFFFFFFu - (unsigned)(kv & 0xFFFFFFFFu);
    unsigned a = idx / 80u;
    unsigned cls = idx - a * 80u;
    const _Float16* rg = Rh + (size_t)t.rBase[slot] + (size_t)a * 4;
    float a0 = anc[(size_t)a * 4 + 0], a1 = anc[(size_t)a * 4 + 1];
    float a2 = anc[(size_t)a * 4 + 2], a3 = anc[(size_t)a * 4 + 3];
    float wa = a2 - a0, ha = a3 - a1;
    float xa = a0 + 0.5f * wa, ya = a1 + 0.5f * ha;
    float dx = (float)rg[0], dy = (float)rg[1];
    float dw = fminf((float)rg[2], SCALE_CLAMP_F), dh = fminf((float)rg[3], SCALE_CLAMP_F);
    float cx = dx * wa + xa, cy = dy * ha + ya;
    float wb = expf(dw) * wa, hb = expf(dh) * ha;
    float x0 = cx - 0.5f * wb, y0 = cy - 0.5f * hb;
    float x1 = cx + 0.5f * wb, y1 = cy + 0.5f * hb;
    x0 = fminf(fmaxf(x0, 0.f), IMG_W_F);
    y0 = fminf(fmaxf(y0, 0.f), IMG_H_F);
    x1 = fminf(fmaxf(x1, 0.f), IMG_W_F);
    y1 = fminf(fmaxf(y1, 0.f), IMG_H_F);
    int o = t.outBase[slot] + tid;
    candB[(size_t)o * 4 + 0] = x0; candB[(size_t)o * 4 + 1] = y0;
    candB[(size_t)o * 4 + 2] = x1; candB[(size_t)o * 4 + 3] = y1;
    candS[o] = (val > SCORE_THR) ? val : 0.f;
    candC[o] = (float)cls;
  }
}

// ---------------- class-aware NMS, shuffle-reduced argmax ----------------
__global__ __launch_bounds__(1024)
void nms_k(const float* __restrict__ cB, const float* __restrict__ cS,
           const float* __restrict__ cC, float* __restrict__ out)
{
  const int n = blockIdx.x;
  const int tid = threadIdx.x;
  const int wid = tid >> 6, lane = tid & 63;
  __shared__ float S[NCAND];
  __shared__ float wv_[16];
  __shared__ int wi_[16];
  __shared__ float bj[5];
  __shared__ int sjs;
  for (int i = tid; i < NCAND; i += 1024) S[i] = cS[n * NCAND + i];
  __syncthreads();
  for (int it = 0; it < MAXDET; ++it) {
    float bv = -1.f; int bix = 0;
    for (int i = tid; i < NCAND; i += 1024) {
      float v = S[i];
      if (v > bv) { bv = v; bix = i; }
    }
#pragma unroll
    for (int d = 32; d > 0; d >>= 1) {
      float v2 = __shfl_down(bv, d);
      int i2 = __shfl_down(bix, d);
      if (v2 > bv || (v2 == bv && i2 < bix)) { bv = v2; bix = i2; }
    }
    if (lane == 0) { wv_[wid] = bv; wi_[wid] = bix; }
    __syncthreads();
    if (tid < 64) {
      float v = (tid < 16) ? wv_[tid] : -2.f;
      int ix = (tid < 16) ? wi_[tid] : 0x7FFFFFFF;
#pragma unroll
      for (int d = 8; d > 0; d >>= 1) {
        float v2 = __shfl_down(v, d);
        int i2 = __shfl_down(ix, d);
        if (v2 > v || (v2 == v && i2 < ix)) { v = v2; ix = i2; }
      }
      if (tid == 0) {
        bj[4] = v; sjs = ix;
        if (v > 0.f) {
          const int j = ix;
          float b0 = cB[(size_t)(n * NCAND + j) * 4 + 0];
          float b1 = cB[(size_t)(n * NCAND + j) * 4 + 1];
          float b2 = cB[(size_t)(n * NCAND + j) * 4 + 2];
          float b3 = cB[(size_t)(n * NCAND + j) * 4 + 3];
          out[((size_t)n * MAXDET + it) * 4 + 0] = b0;
          out[((size_t)n * MAXDET + it) * 4 + 1] = b1;
          out[((size_t)n * MAXDET + it) * 4 + 2] = b2;
          out[((size_t)n * MAXDET + it) * 4 + 3] = b3;
          out[800 + n * MAXDET + it] = v;
          out[1000 + n * MAXDET + it] = cC[n * NCAND + j];
          float off = cC[n * NCAND + j] * 4096.f;
          bj[0] = b0 + off; bj[1] = b1 + off; bj[2] = b2 + off; bj[3] = b3 + off;
        }
      }
    }
    __syncthreads();
    const float mv = bj[4];
    const int j = sjs;
    if (mv <= 0.f) {
      float b0 = cB[(size_t)(n * NCAND) * 4 + 0], b1 = cB[(size_t)(n * NCAND) * 4 + 1];
      float b2 = cB[(size_t)(n * NCAND) * 4 + 2], b3 = cB[(size_t)(n * NCAND) * 4 + 3];
      float c0 = cC[n * NCAND];
      for (int t2 = it + tid; t2 < MAXDET; t2 += 1024) {
        out[((size_t)n * MAXDET + t2) * 4 + 0] = b0;
        out[((size_t)n * MAXDET + t2) * 4 + 1] = b1;
        out[((size_t)n * MAXDET + t2) * 4 + 2] = b2;
        out[((size_t)n * MAXDET + t2) * 4 + 3] = b3;
        out[800 + n * MAXDET + t2] = 0.f;
        out[1000 + n * MAXDET + t2] = c0;
      }
      return;
    }
    const float jx0 = bj[0], jy0 = bj[1], jx1 = bj[2], jy1 = bj[3];
    const float aj = (jx1 - jx0) * (jy1 - jy0);
    for (int i = tid; i < NCAND; i += 1024) {
      if (i == j) { S[i] = 0.f; continue; }
      if (S[i] == 0.f) continue;
      float off = cC[n * NCAND + i] * 4096.f;
      float x0 = cB[(size_t)(n * NCAND + i) * 4 + 0] + off;
      float y0 = cB[(size_t)(n * NCAND + i) * 4 + 1] + off;
      float x1 = cB[(size_t)(n * NCAND + i) * 4 + 2] + off;
      float y1 = cB[(size_t)(n * NCAND + i) * 4 + 3] + off;
      float lx = fmaxf(jx0, x0), ly = fmaxf(jy0, y0);
      float rx = fminf(jx1, x1), ry = fminf(jy1, y1);
      float iw = fmaxf(rx - lx, 0.f), ih = fmaxf(ry - ly, 0.f);
      float inter = iw * ih;
      float ai = (x1 - x0) * (y1 - y0);
      float iou = inter / (aj + ai - inter + 1e-9f);
      if (iou > NMS_THR) S[i] = 0.f;
    }
    __syncthreads();
  }
}

// ---------------- host ----------------
extern "C" void kernel_launch(void* const* d_in, const int* in_sizes, int n_in,
                              void* d_out, int out_size, void* d_ws, size_t ws_size,
                              hipStream_t stream)
{
  static const int LH[5] = {100, 50, 25, 13, 7};
  static const int LW[5] = {152, 76, 38, 19, 10};
  static const int LHW[5] = {15200, 3800, 950, 247, 70};
  static const int NTK[5] = {1000, 1000, 1000, 1000, 630};
  static const int OFFS[5] = {0, 1000, 2000, 3000, 4000};
  static const unsigned ACTOFF[5] = {0u, 8042496u, 10119168u, 10672128u, 10833408u};
  static const int CUMT128[6] = {0, 238, 298, 313, 317, 319};
  static const int CUMR[6] = {0, 100, 150, 175, 188, 195};
  static const int ROFF[5] = {0, 1094400, 1368000, 1436400, 1454184};
  static const int POFF14[4] = {0, 2736000, 3420000, 3597840};

  const float* feat[5]; const float* anc[5];
  for (int l = 0; l < 5; ++l) {
    feat[l] = (const float*)d_in[l];
    anc[l] = (const float*)d_in[13 + l];
  }
  const float* csw = (const float*)d_in[5];
  const float* csb = (const float*)d_in[6];
  const float* bsw = (const float*)d_in[7];
  const float* bsb = (const float*)d_in[8];
  const float* scw = (const float*)d_in[9];
  const float* scb = (const float*)d_in[10];
  const float* bpw = (const float*)d_in[11];
  const float* bpb = (const float*)d_in[12];

  float* wsF = (float*)d_ws;
  size_t o = 0;
  _Float16* actBase = (_Float16*)(wsF + o); o += (size_t)4 * BUF_HALFS / 2;
  _Float16* wpk = (_Float16*)(wsF + o); o += 3317760;
  float* P0 = wsF + o; o += 10944000;
  _Float16* Rh = (_Float16*)(wsF + o); o += 729612;
  float* candB = wsF + o; o += (size_t)NIMG * NCAND * 4;
  float* candS = wsF + o; o += NIMG * NCAND;
  float* candC = wsF + o; o += NIMG * NCAND;
  float* candV = wsF + o; o += NSLOT * 1024;
  unsigned* candI = (unsigned*)(wsF + o); o += NSLOT * 1024;
  unsigned* eqI = (unsigned*)(wsF + o); o += NSLOT * 8192;
  unsigned* tkbuf = (unsigned*)(wsF + o); o += (size_t)NSLOT * TK_SLOT_U32;
  if (ws_size < o * sizeof(float)) return;  // ~154 MB required

  _Float16* X = actBase;
  _Float16* A = X + BUF_HALFS;
  _Float16* B = A + BUF_HALFS;
  _Float16* C = B + BUF_HALFS;
  float* P1 = (float*)A;        // A+B region, free after towers (L0 img1)
  const int PX_L14_IMG0 = 0;
  const int PC_L14_IMG1 = 16416000;
  float* out = (float*)d_out;

  // weight prepack: one dispatch
  {
    PPTab pp;
    static const int PPC[11] = {0, 73728, 147456, 221184, 294912, 368640,
                                442368, 516096, 589824, 811008, 829440};
    for (int i = 0; i < 11; ++i) pp.cum[i] = PPC[i];
    for (int i = 0; i < 4; ++i) {
      pp.src[i] = csw + (size_t)i * 589824; pp.dstOff[i] = WOFF_CLS_T(i);
      pp.Cout[i] = 256; pp.nCoF[i] = 8;
      pp.src[4 + i] = bsw + (size_t)i * 589824; pp.dstOff[4 + i] = WOFF_BBX_T(i);
      pp.Cout[4 + i] = 256; pp.nCoF[4 + i] = 8;
    }
    pp.src[8] = scw; pp.dstOff[8] = WOFF_CLS_H; pp.Cout[8] = 720; pp.nCoF[8] = 24;
    pp.src[9] = bpw; pp.dstOff[9] = WOFF_BBX_H; pp.Cout[9] = 36; pp.nCoF[9] = 2;
    prepack_k<<<dim3(3240), dim3(256), 0, stream>>>(wpk, pp);
  }

  // halo-ring zero
  {
    HaloTab hzt;
    static const int HCUM[6] = {0, 508, 764, 894, 962, 1000};
    for (int i = 0; i < 6; ++i) hzt.cumPx[i] = HCUM[i];
    for (int l = 0; l < 5; ++l) {
      hzt.Hp[l] = LH[l] + 2; hzt.Wp[l] = LW[l] + 2; hzt.actOff[l] = ACTOFF[l];
    }
    halo_k<<<dim3((128000 + 255) / 256), dim3(256), 0, stream>>>(X, hzt);
  }

  ConvTab ct;
  CvtTab vt;
  for (int l = 0; l < 5; ++l) {
    ct.H[l] = LH[l]; ct.W[l] = LW[l]; ct.actOff[l] = ACTOFF[l];
    vt.f[l] = feat[l]; vt.H[l] = LH[l]; vt.W[l] = LW[l]; vt.actOff[l] = ACTOFF[l];
  }
  for (int i = 0; i < 6; ++i) { ct.cum[i] = CUMT128[i]; vt.cumR[i] = CUMR[i]; }

  convert_k<<<dim3(195, NIMG), dim3(256), 0, stream>>>(X, vt);

  // towers: (X,X)->(A,B); (A,B)->(C,X); (C,X)->(A,B); (A,B)->(C,X)
  tower_k<<<dim3(4, 319), dim3(256), 0, stream>>>(X, X, wpk, csb + 0, bsb + 0, A, B,
      WOFF_CLS_T(0), WOFF_BBX_T(0), ct);
  tower_k<<<dim3(4, 319), dim3(256), 0, stream>>>(A, B, wpk, csb + 256, bsb + 256, C, X,
      WOFF_CLS_T(1), WOFF_BBX_T(1), ct);
  tower_k<<<dim3(4, 319), dim3(256), 0, stream>>>(C, X, wpk, csb + 512, bsb + 512, A, B,
      WOFF_CLS_T(2), WOFF_BBX_T(2), ct);
  tower_k<<<dim3(4, 319), dim3(256), 0, stream>>>(A, B, wpk, csb + 768, bsb + 768, C, X,
      WOFF_CLS_T(3), WOFF_BBX_T(3), ct);
  // cls acts in C, bbox acts in X; A,B free -> P1

  const int p0Off = (int)(P0 - wsF);
  const int p1Off = (int)(P1 - wsF);

  // ---- heads (2 dispatches; L0 first, then L1-4 which overwrites L0 act regions) ----
  {
    HeadTab ht = {};
    ht.cum[0] = 0; ht.cum[1] = 60;
    for (int i = 2; i < 6; ++i) ht.cum[i] = 0x7FFFFFFF;
    ht.actOff[0] = ACTOFF[0]; ht.H[0] = LH[0]; ht.W[0] = LW[0];
    ht.pOffL[0] = p0Off; ht.pStride[0] = p1Off - p0Off;
    ht.rOffL[0] = ROFF[0];
    head_k<<<dim3(13, 60, 2), dim3(256), 0, stream>>>(C, X, wpk, scb, bpb, wsF, Rh, ht);
  }
  {
    HeadTab ht = {};
    static const int CUMH14[6] = {0, 15, 19, 20, 21, 0x7FFFFFFF};
    for (int i = 0; i < 6; ++i) ht.cum[i] = CUMH14[i];
    for (int i = 0; i < 4; ++i) {
      int l = i + 1;
      ht.actOff[i] = ACTOFF[l]; ht.H[i] = LH[l]; ht.W[i] = LW[l];
      ht.pOffL[i] = PX_L14_IMG0 + POFF14[i];
      ht.pStride[i] = PC_L14_IMG1 - PX_L14_IMG0;
      ht.rOffL[i] = ROFF[l];
    }
    head_k<<<dim3(13, 21, 2), dim3(256), 0, stream>>>(C, X, wpk, scb, bpb, wsF, Rh, ht);
  }

  // ---- single 10-slot top-k batch ----
  {
    TKTab tk = {};
    tk.pOff[0] = p0Off; tk.pOff[1] = p1Off;
    for (int img = 0; img < 2; ++img) {
      tk.M[img] = LHW[0] * 720; tk.kk[img] = NTK[0];
      tk.rBase[img] = ROFF[0] + img * LHW[0] * 36;
      tk.outBase[img] = img * NCAND + OFFS[0];
      tk.anc[img] = anc[0];
    }
    for (int s = 2; s < 10; ++s) {
      int i = s - 2;
      int l = (i & 3) + 1, img = i >> 2;
      tk.pOff[s] = (img ? PC_L14_IMG1 : PX_L14_IMG0) + POFF14[l - 1];
      tk.M[s] = LHW[l] * 720;
      tk.kk[s] = NTK[l];
      tk.rBase[s] = ROFF[l] + img * LHW[l] * 36;
      tk.outBase[s] = img * NCAND + OFFS[l];
      tk.anc[s] = anc[l];
    }
    hipMemsetAsync(tkbuf, 0, (size_t)NSLOT * TK_SLOT_U32 * 4, stream);
    hist_coarse_k<<<dim3(256, NSLOT), dim3(256), 0, stream>>>(wsF, tkbuf, tk);
    radix_scan_k<<<dim3(NSLOT), dim3(1024), 0, stream>>>(tkbuf, tk, 0);
    hist_fine_k<<<dim3(256, NSLOT), dim3(256), 0, stream>>>(wsF, tkbuf, tk);
    radix_scan_k<<<dim3(NSLOT), dim3(1024), 0, stream>>>(tkbuf, tk, 1);
    compact_k<<<dim3(256, NSLOT), dim3(256), 0, stream>>>(wsF, tkbuf, candV, candI, eqI, tk);
    finalize_k<<<dim3(NSLOT), dim3(1024), 0, stream>>>(candV, candI, eqI, tkbuf, Rh, tk,
                                                       candB, candS, candC);
  }
  nms_k<<<dim3(NIMG), dim3(1024), 0, stream>>>(candB, candS, candC, out);
}